// Round 15
// baseline (90.473 us; speedup 1.0000x reference)
//
#include <hip/hip_runtime.h>

#define B_   2
#define H_   16
#define S_   2048
#define D_   64
#define BQ   128    // q rows per block (16 per wave, 8 waves)
#define NW   8
// fold 1/sqrt(64) * log2(e) into Q so softmax works in exp2 domain
#define QSCALE 0.18033688011112042f
#define DEFER_THR 8.0f

typedef _Float16 f16x4 __attribute__((ext_vector_type(4)));
typedef _Float16 f16x8 __attribute__((ext_vector_type(8)));
typedef float    f32x4 __attribute__((ext_vector_type(4)));

typedef const unsigned int __attribute__((address_space(1))) gu32;
typedef unsigned int       __attribute__((address_space(3))) lu32;

#define KBYTES_PER_HEAD (S_ * 128)                       // 256 KB f16 per head per tensor
#define WS_V_OFF ((size_t)B_ * H_ * KBYTES_PER_HEAD)     // 8.4 MB
#define WS_NEED  (2 * WS_V_OFF)

// ---------------- fused prepass: K -> swizzled f16 tiles (LDS image, verified);
// V -> PLAIN transposed f16 tiles [d][k] (read direct from L2, no swizzle:
// 4 lanes/row read one aligned 64B sector)
__global__ __launch_bounds__(256) void prep_kv(const float* __restrict__ K,
                                               const float* __restrict__ V,
                                               char* __restrict__ ws)
{
    if (blockIdx.x < (B_ * H_ * S_ * 8) / 256) {
        const int gidx = blockIdx.x * 256 + threadIdx.x;
        const int gcol = gidx & 7;
        const int srow = gidx >> 3;                      // bh*S + s
        const float4* src = (const float4*)(K + (size_t)srow * D_ + gcol * 8);
        float4 a = src[0], b = src[1];
        f16x8 h;
        h[0] = (_Float16)a.x; h[1] = (_Float16)a.y; h[2] = (_Float16)a.z; h[3] = (_Float16)a.w;
        h[4] = (_Float16)b.x; h[5] = (_Float16)b.y; h[6] = (_Float16)b.z; h[7] = (_Float16)b.w;
        const int s  = srow & (S_ - 1);
        const int bh = srow >> 11;
        size_t off = (size_t)bh * KBYTES_PER_HEAD + (size_t)(s >> 6) * 8192
                   + (s & 63) * 128 + ((gcol ^ (s & 7)) << 4);
        *(f16x8*)(ws + off) = h;
    } else {
        __shared__ _Float16 Vl[64][72];
        const int tile = blockIdx.x - (B_ * H_ * S_ * 8) / 256;  // bh*32 + t
        const int bh = tile >> 5, t = tile & 31;
        const float* vb = V + ((size_t)bh * S_ + t * 64) * D_;
        const int tid = threadIdx.x;
        #pragma unroll
        for (int it = 0; it < 2; ++it) {
            const int row = (tid >> 3) + it * 32;
            const int c8  = (tid & 7) * 8;
            const float4* p = (const float4*)(vb + row * D_ + c8);
            float4 a = p[0], b = p[1];
            f16x8 h;
            h[0] = (_Float16)a.x; h[1] = (_Float16)a.y; h[2] = (_Float16)a.z; h[3] = (_Float16)a.w;
            h[4] = (_Float16)b.x; h[5] = (_Float16)b.y; h[6] = (_Float16)b.z; h[7] = (_Float16)b.w;
            *(f16x8*)&Vl[row][c8] = h;
        }
        __syncthreads();
        char* out = ws + WS_V_OFF + (size_t)bh * KBYTES_PER_HEAD + t * 8192;
        #pragma unroll
        for (int it = 0; it < 2; ++it) {
            const int task = tid + it * 256;
            const int d = task >> 3, kg = task & 7;
            f16x8 h;
            #pragma unroll
            for (int j = 0; j < 8; ++j) h[j] = Vl[kg * 8 + j][d];
            *(f16x8*)(out + d * 128 + kg * 16) = h;      // plain [d][k], no swizzle
        }
    }
}

// ---------------- pipeline pieces (QK/P layouts identical to verified R12) ----------------

// QK^T swapped: A = K rows, B = Q  ->  accS[k-sub = g*4+r][q = l15]
template<bool MASK>
__device__ __forceinline__ void qk_tile(
    const _Float16* __restrict__ Kb, const f16x8 aq[2], f32x4 (&accS)[4],
    int g, int l15, int sx, int dq)
{
    #pragma unroll
    for (int s = 0; s < 4; ++s) accS[s] = (f32x4){0.f, 0.f, 0.f, 0.f};
    __builtin_amdgcn_s_setprio(1);
    #pragma unroll
    for (int sub = 0; sub < 4; ++sub) {
        if (MASK && (sub * 16 > dq + 15)) continue;      // wave-uniform fully-masked sub
        #pragma unroll
        for (int kc = 0; kc < 2; ++kc) {
            f16x8 ak = *(const f16x8*)(Kb + ((sub * 16 + l15) * 64 + (((kc * 4 + g) ^ sx) << 3)));
            accS[sub] = __builtin_amdgcn_mfma_f32_16x16x32_f16(ak, aq[kc], accS[sub], 0, 0, 0);
        }
    }
    __builtin_amdgcn_s_setprio(0);
}

// online softmax (exp2 domain, defer-max) + PV; V fragments arrive preloaded
// from L2 (av0 = k 0..31 slice, av1 = k 32..63 slice).
template<bool MASK>
__device__ __forceinline__ void smpv_tile(
    const f16x8 av0[4], const f16x8 av1[4], _Float16 (*__restrict__ Plw)[72],
    f32x4 (&accS)[4], f32x4 accO[4], float& m_r, float& l_r,
    int g, int l15, int dq)
{
    auto msk = [&](int sub, int r) -> float {
        float s = accS[sub][r];
        if (MASK) {
            if (sub * 16 > dq + 15) s = -1e30f;
            else if (sub * 16 + 15 > dq) {
                if (sub * 16 + g * 4 + r > dq + l15) s = -1e30f;
            }
        }
        return s;
    };

    float pmax = -1e30f;
    #pragma unroll
    for (int sub = 0; sub < 4; ++sub)
        #pragma unroll
        for (int r = 0; r < 4; ++r) pmax = fmaxf(pmax, msk(sub, r));

    // defer-max (T13): wave-uniform ballot; common case no cross-lane ops
    if (!__all(pmax <= m_r + DEFER_THR)) {
        float mx = pmax;
        mx = fmaxf(mx, __shfl_xor(mx, 16));
        mx = fmaxf(mx, __shfl_xor(mx, 32));
        const float mnew  = fmaxf(m_r, mx);
        const float alpha = __builtin_amdgcn_exp2f(m_r - mnew);
        l_r *= alpha;
        #pragma unroll
        for (int d = 0; d < 4; ++d)
            #pragma unroll
            for (int r = 0; r < 4; ++r) accO[d][r] *= alpha;
        m_r = mnew;
    }

    // exp2 with (stale-by-<=THR) m_r: values bounded by 2^THR = 256, f16-safe
    float rs = 0.f;
    #pragma unroll
    for (int sub = 0; sub < 4; ++sub) {
        float p0 = __builtin_amdgcn_exp2f(msk(sub, 0) - m_r);
        float p1 = __builtin_amdgcn_exp2f(msk(sub, 1) - m_r);
        float p2 = __builtin_amdgcn_exp2f(msk(sub, 2) - m_r);
        float p3 = __builtin_amdgcn_exp2f(msk(sub, 3) - m_r);
        rs += (p0 + p1) + (p2 + p3);
        f16x4 q4;
        q4[0] = (_Float16)p0; q4[1] = (_Float16)p1;
        q4[2] = (_Float16)p2; q4[3] = (_Float16)p3;
        *(f16x4*)&Plw[l15][sub * 16 + g * 4] = q4;       // row q=l15, col k
    }
    l_r += rs;

    asm volatile("s_waitcnt lgkmcnt(0)" ::: "memory");   // wave-local Pl write->read fence
    __builtin_amdgcn_sched_barrier(0);

    f16x8 pb0 = *(const f16x8*)&Plw[l15][g * 8];
    f16x8 pb1 = *(const f16x8*)&Plw[l15][32 + g * 8];

    // PV swapped: A = V^T rows (d) from registers (L2-loaded), B = P^T
    __builtin_amdgcn_s_setprio(1);
    #pragma unroll
    for (int d = 0; d < 4; ++d)
        accO[d] = __builtin_amdgcn_mfma_f32_16x16x32_f16(av0[d], pb0, accO[d], 0, 0, 0);
    #pragma unroll
    for (int d = 0; d < 4; ++d)
        accO[d] = __builtin_amdgcn_mfma_f32_16x16x32_f16(av1[d], pb1, accO[d], 0, 0, 0);
    __builtin_amdgcn_s_setprio(0);
}

__global__ __launch_bounds__(512, 4) void attn_main(
    const float* __restrict__ Q, const char* __restrict__ ws, float* __restrict__ O)
{
    __shared__ _Float16 SM[3][4096];        // triple buffer: K tiles only (8 KB each)
    __shared__ _Float16 Pl[NW][16][72];

    const int tid  = threadIdx.x;
    const int lane = tid & 63;
    const int w    = tid >> 6;              // wave 0..7
    const int g    = lane >> 4;
    const int l15  = lane & 15;
    const int sx   = l15 & 7;

    // Balanced heavy+light strip pairing with head->XCD affinity (id%8 = bh%8)
    const int id    = blockIdx.x;
    const int bh    = id & 31;
    const int qi    = id >> 5;              // 0..15
    const int qt    = (id < 256) ? (15 - qi) : (qi - 8);
    const int qbase = qt * BQ;

    const char* kbase = ws + (size_t)bh * KBYTES_PER_HEAD;
    const char* vbase = ws + WS_V_OFF + (size_t)bh * KBYTES_PER_HEAD;

    // hoist Q fragments, pre-scaled into exp2 domain
    f16x8 aq[2];
    {
        const float* qrow = Q + ((size_t)bh * S_ + qbase + w * 16 + l15) * D_;
        #pragma unroll
        for (int kc = 0; kc < 2; ++kc) {
            const float4* p = (const float4*)(qrow + kc * 32 + g * 8);
            float4 x0 = p[0], x1 = p[1];
            f16x8 h;
            h[0] = (_Float16)(x0.x * QSCALE); h[1] = (_Float16)(x0.y * QSCALE);
            h[2] = (_Float16)(x0.z * QSCALE); h[3] = (_Float16)(x0.w * QSCALE);
            h[4] = (_Float16)(x1.x * QSCALE); h[5] = (_Float16)(x1.y * QSCALE);
            h[6] = (_Float16)(x1.z * QSCALE); h[7] = (_Float16)(x1.w * QSCALE);
            aq[kc] = h;
        }
    }

    f32x4 accO[4];
    #pragma unroll
    for (int i = 0; i < 4; ++i) accO[i] = (f32x4){0.f, 0.f, 0.f, 0.f};
    float m_r = -1e30f, l_r = 0.f;
    f32x4 accSA[4], accSB[4];
    f16x8 av0[4], av1[4];

    const int nt  = 2 * qt + 2;             // 64-wide tiles; last two straddle the diagonal
    const int dqw = qbase + w * 16;         // wave q-row base

    // rotating K buffers: bQK = tile t, bST = stage target (t+1), spare
    _Float16* bQK = &SM[0][0];
    _Float16* bST = &SM[1][0];
    _Float16* bSP = &SM[2][0];

    // stage K tile t: 8 x 1KB chunks, 1 per wave (pre-swizzled source, linear dest)
    auto STAGE = [&](int t, _Float16* dst) {
        const char* src = kbase + (size_t)t * 8192 + w * 1024 + lane * 16;
        __builtin_amdgcn_global_load_lds((gu32*)src, (lu32*)(dst + w * 512), 16, 0, 0);
    };
    // V(t) fragments direct from L2: kc-half into av[4]; row d*16+l15, 64B/row sector
    auto LOADV = [&](int t, f16x8 (&av)[4], int kc) {
        const char* vt = vbase + (size_t)t * 8192 + ((kc * 4 + g) << 4) + l15 * 128;
        #pragma unroll
        for (int d = 0; d < 4; ++d)
            av[d] = *(const f16x8*)(vt + d * 2048);      // (d*16)*128 bytes
    };
    auto SYNC = []() {
        asm volatile("s_waitcnt vmcnt(0)" ::: "memory");
        __builtin_amdgcn_s_barrier();
    };
    auto ROT = [&]() { _Float16* tmp = bSP; bSP = bQK; bQK = bST; bST = tmp; };

    STAGE(0, bQK);

    // ---- window 0: QK(0) -> A
    SYNC();
    STAGE(1, bST);
    if (qt == 0) qk_tile<true >(bQK, aq, accSA, g, l15, sx, dqw);
    else         qk_tile<false>(bQK, aq, accSA, g, l15, sx, 0);
    ROT();

    // ---- window 1: QK(1) -> B, SM+PV(0) from A
    SYNC();
    LOADV(0, av0, 0);
    if (nt > 2) STAGE(2, bST);
    if (qt == 0) {
        qk_tile<true >(bQK, aq, accSB, g, l15, sx, dqw - 64);
        LOADV(0, av1, 1);
        smpv_tile<true >(av0, av1, Pl[w], accSA, accO, m_r, l_r, g, l15, dqw);
    } else {
        qk_tile<false>(bQK, aq, accSB, g, l15, sx, 0);
        LOADV(0, av1, 1);
        smpv_tile<false>(av0, av1, Pl[w], accSA, accO, m_r, l_r, g, l15, 0);
    }
    ROT();

    // ---- steady windows: tiles 2i (->A) and 2i+1 (->B), all unmasked
    for (int i = 1; i < qt; ++i) {
        const int t0 = 2 * i;
        SYNC();
        LOADV(t0 - 1, av0, 0);
        STAGE(t0 + 1, bST);
        qk_tile<false>(bQK, aq, accSA, g, l15, sx, 0);
        LOADV(t0 - 1, av1, 1);
        smpv_tile<false>(av0, av1, Pl[w], accSB, accO, m_r, l_r, g, l15, 0);
        ROT();
        SYNC();
        LOADV(t0, av0, 0);
        STAGE(t0 + 2, bST);
        qk_tile<false>(bQK, aq, accSB, g, l15, sx, 0);
        LOADV(t0, av1, 1);
        smpv_tile<false>(av0, av1, Pl[w], accSA, accO, m_r, l_r, g, l15, 0);
        ROT();
    }

    // ---- masked pair (tiles nt-2 -> A, nt-1 -> B), only for qt >= 1
    if (qt >= 1) {
        SYNC();
        LOADV(nt - 3, av0, 0);
        STAGE(nt - 1, bST);
        qk_tile<true >(bQK, aq, accSA, g, l15, sx, dqw - (nt - 2) * 64);
        LOADV(nt - 3, av1, 1);
        smpv_tile<false>(av0, av1, Pl[w], accSB, accO, m_r, l_r, g, l15, 0);
        ROT();
        SYNC();
        LOADV(nt - 2, av0, 0);
        qk_tile<true >(bQK, aq, accSB, g, l15, sx, dqw - (nt - 1) * 64);
        LOADV(nt - 2, av1, 1);
        smpv_tile<true >(av0, av1, Pl[w], accSA, accO, m_r, l_r, g, l15, dqw - (nt - 2) * 64);
        ROT();
    }

    // ---- epilogue window: SM+PV(nt-1) from B
    LOADV(nt - 1, av0, 0);
    LOADV(nt - 1, av1, 1);
    smpv_tile<true>(av0, av1, Pl[w], accSB, accO, m_r, l_r, g, l15, dqw - (nt - 1) * 64);

    // epilogue: finish deferred row-sum (once per kernel), store O
    float l = l_r;
    l += __shfl_xor(l, 16);
    l += __shfl_xor(l, 32);
    const float inv = 1.0f / l;
    float* orow = O + ((size_t)bh * S_ + qbase + w * 16 + l15) * D_;
    #pragma unroll
    for (int d = 0; d < 4; ++d) {
        f32x4 o = accO[d] * inv;
        *(f32x4*)&orow[d * 16 + g * 4] = o;
    }
}

extern "C" void kernel_launch(void* const* d_in, const int* in_sizes, int n_in,
                              void* d_out, int out_size, void* d_ws, size_t ws_size,
                              hipStream_t stream) {
    const float* q = (const float*)d_in[0];
    const float* k = (const float*)d_in[1];
    const float* v = (const float*)d_in[2];
    // d_in[3] (mask) intentionally never read — causality computed in-kernel
    float* o = (float*)d_out;
    char* ws = (char*)d_ws;

    if (ws_size < WS_NEED) return;

    const int kblocks = (B_ * H_ * S_ * 8) / 256;        // 1024
    const int vblocks = B_ * H_ * (S_ / 64);             // 1024
    prep_kv<<<kblocks + vblocks, 256, 0, stream>>>(k, v, ws);
    attn_main<<<(S_ / BQ) * B_ * H_, 512, 0, stream>>>(q, ws, o);
}

// Round 16
// 50.924 us; speedup vs baseline: 1.7766x; 1.7766x over previous
//
#include <hip/hip_runtime.h>

#define B_   2
#define H_   16
#define S_   2048
#define D_   64
#define BQ   128    // q rows per block (16 per wave, 8 waves)
#define BK   64
#define NW   8
// fold 1/sqrt(64) * log2(e) into Q so softmax works in exp2 domain
#define QSCALE 0.18033688011112042f
#define DEFER_THR 8.0f

typedef _Float16 f16x4 __attribute__((ext_vector_type(4)));
typedef _Float16 f16x8 __attribute__((ext_vector_type(8)));
typedef float    f32x4 __attribute__((ext_vector_type(4)));

typedef const unsigned int __attribute__((address_space(1))) gu32;
typedef unsigned int       __attribute__((address_space(3))) lu32;

#define KBYTES_PER_HEAD (S_ * 128)                       // 256 KB f16 per head per tensor
#define WS_V_OFF ((size_t)B_ * H_ * KBYTES_PER_HEAD)     // 8.4 MB
#define WS_NEED  (2 * WS_V_OFF)

// ---------------- fused prepass (verified, unchanged): K -> swizzled f16 tiles,
// V -> transposed swizzled f16 tiles
__global__ __launch_bounds__(256) void prep_kv(const float* __restrict__ K,
                                               const float* __restrict__ V,
                                               char* __restrict__ ws)
{
    if (blockIdx.x < (B_ * H_ * S_ * 8) / 256) {
        const int gidx = blockIdx.x * 256 + threadIdx.x;
        const int gcol = gidx & 7;
        const int srow = gidx >> 3;                      // bh*S + s
        const float4* src = (const float4*)(K + (size_t)srow * D_ + gcol * 8);
        float4 a = src[0], b = src[1];
        f16x8 h;
        h[0] = (_Float16)a.x; h[1] = (_Float16)a.y; h[2] = (_Float16)a.z; h[3] = (_Float16)a.w;
        h[4] = (_Float16)b.x; h[5] = (_Float16)b.y; h[6] = (_Float16)b.z; h[7] = (_Float16)b.w;
        const int s  = srow & (S_ - 1);
        const int bh = srow >> 11;
        size_t off = (size_t)bh * KBYTES_PER_HEAD + (size_t)(s >> 6) * 8192
                   + (s & 63) * 128 + ((gcol ^ (s & 7)) << 4);
        *(f16x8*)(ws + off) = h;
    } else {
        __shared__ _Float16 Vl[64][72];
        const int tile = blockIdx.x - (B_ * H_ * S_ * 8) / 256;  // bh*32 + t
        const int bh = tile >> 5, t = tile & 31;
        const float* vb = V + ((size_t)bh * S_ + t * 64) * D_;
        const int tid = threadIdx.x;
        #pragma unroll
        for (int it = 0; it < 2; ++it) {
            const int row = (tid >> 3) + it * 32;
            const int c8  = (tid & 7) * 8;
            const float4* p = (const float4*)(vb + row * D_ + c8);
            float4 a = p[0], b = p[1];
            f16x8 h;
            h[0] = (_Float16)a.x; h[1] = (_Float16)a.y; h[2] = (_Float16)a.z; h[3] = (_Float16)a.w;
            h[4] = (_Float16)b.x; h[5] = (_Float16)b.y; h[6] = (_Float16)b.z; h[7] = (_Float16)b.w;
            *(f16x8*)&Vl[row][c8] = h;
        }
        __syncthreads();
        char* out = ws + WS_V_OFF + (size_t)bh * KBYTES_PER_HEAD + t * 8192;
        #pragma unroll
        for (int it = 0; it < 2; ++it) {
            const int task = tid + it * 256;
            const int d = task >> 3, kg = task & 7;
            f16x8 h;
            #pragma unroll
            for (int j = 0; j < 8; ++j) h[j] = Vl[kg * 8 + j][d];
            *(f16x8*)(out + d * 128 + ((kg ^ (d & 7)) << 4)) = h;
        }
    }
}

// ---------------- pipeline pieces (layouts identical to verified R8 kernel) ----------------

// QK^T swapped: A = K rows, B = Q  ->  accS[k-sub = g*4+r][q = l15]
template<bool MASK>
__device__ __forceinline__ void qk_tile(
    const _Float16* __restrict__ Kb, const f16x8 aq[2], f32x4 (&accS)[4],
    int g, int l15, int sx, int dq)
{
    #pragma unroll
    for (int s = 0; s < 4; ++s) accS[s] = (f32x4){0.f, 0.f, 0.f, 0.f};
    __builtin_amdgcn_s_setprio(1);
    #pragma unroll
    for (int sub = 0; sub < 4; ++sub) {
        if (MASK && (sub * 16 > dq + 15)) continue;      // wave-uniform fully-masked sub
        #pragma unroll
        for (int kc = 0; kc < 2; ++kc) {
            f16x8 ak = *(const f16x8*)(Kb + ((sub * 16 + l15) * 64 + (((kc * 4 + g) ^ sx) << 3)));
            accS[sub] = __builtin_amdgcn_mfma_f32_16x16x32_f16(ak, aq[kc], accS[sub], 0, 0, 0);
        }
    }
    __builtin_amdgcn_s_setprio(0);
}

// online softmax (exp2 domain, defer-max) + PV on the PREVIOUS tile's scores
template<bool MASK>
__device__ __forceinline__ void smpv_tile(
    const _Float16* __restrict__ SMb, _Float16 (*__restrict__ Plw)[72],
    f32x4 (&accS)[4], f32x4 accO[4], float& m_r, float& l_r,
    int g, int l15, int sx, int dq)
{
    const _Float16* Vb = SMb + 4096;

    auto msk = [&](int sub, int r) -> float {
        float s = accS[sub][r];
        if (MASK) {
            if (sub * 16 > dq + 15) s = -1e30f;
            else if (sub * 16 + 15 > dq) {
                if (sub * 16 + g * 4 + r > dq + l15) s = -1e30f;
            }
        }
        return s;
    };

    float pmax = -1e30f;
    #pragma unroll
    for (int sub = 0; sub < 4; ++sub)
        #pragma unroll
        for (int r = 0; r < 4; ++r) pmax = fmaxf(pmax, msk(sub, r));

    // defer-max (T13): wave-uniform ballot; common case no cross-lane ops
    if (!__all(pmax <= m_r + DEFER_THR)) {
        float mx = pmax;
        mx = fmaxf(mx, __shfl_xor(mx, 16));
        mx = fmaxf(mx, __shfl_xor(mx, 32));
        const float mnew  = fmaxf(m_r, mx);
        const float alpha = __builtin_amdgcn_exp2f(m_r - mnew);
        l_r *= alpha;
        #pragma unroll
        for (int d = 0; d < 4; ++d)
            #pragma unroll
            for (int r = 0; r < 4; ++r) accO[d][r] *= alpha;
        m_r = mnew;
    }

    // exp2 with (stale-by-<=THR) m_r: values bounded by 2^THR = 256, f16-safe
    float rs = 0.f;
    #pragma unroll
    for (int sub = 0; sub < 4; ++sub) {
        float p0 = __builtin_amdgcn_exp2f(msk(sub, 0) - m_r);
        float p1 = __builtin_amdgcn_exp2f(msk(sub, 1) - m_r);
        float p2 = __builtin_amdgcn_exp2f(msk(sub, 2) - m_r);
        float p3 = __builtin_amdgcn_exp2f(msk(sub, 3) - m_r);
        rs += (p0 + p1) + (p2 + p3);
        f16x4 q4;
        q4[0] = (_Float16)p0; q4[1] = (_Float16)p1;
        q4[2] = (_Float16)p2; q4[3] = (_Float16)p3;
        *(f16x4*)&Plw[l15][sub * 16 + g * 4] = q4;       // row q=l15, col k
    }
    l_r += rs;

    asm volatile("s_waitcnt lgkmcnt(0)" ::: "memory");   // wave-local Pl write->read fence
    __builtin_amdgcn_sched_barrier(0);

    f16x8 pb0 = *(const f16x8*)&Plw[l15][g * 8];
    f16x8 pb1 = *(const f16x8*)&Plw[l15][32 + g * 8];

    // PV swapped: A = V^T rows (d), B = P^T -> accO[dsub]: d = dsub*16+g*4+r, q = l15
    __builtin_amdgcn_s_setprio(1);
    #pragma unroll
    for (int d = 0; d < 4; ++d) {
        f16x8 av0 = *(const f16x8*)(Vb + ((d * 16 + l15) * 64 + (((0 * 4 + g) ^ sx) << 3)));
        accO[d] = __builtin_amdgcn_mfma_f32_16x16x32_f16(av0, pb0, accO[d], 0, 0, 0);
        f16x8 av1 = *(const f16x8*)(Vb + ((d * 16 + l15) * 64 + (((1 * 4 + g) ^ sx) << 3)));
        accO[d] = __builtin_amdgcn_mfma_f32_16x16x32_f16(av1, pb1, accO[d], 0, 0, 0);
    }
    __builtin_amdgcn_s_setprio(0);
}

__global__ __launch_bounds__(512, 4) void attn_main(
    const float* __restrict__ Q, const char* __restrict__ ws, float* __restrict__ O)
{
    __shared__ _Float16 SM[3][8192];        // triple buffer: [ K 0..4095 | V 4096..8191 ]
    __shared__ _Float16 Pl[NW][16][72];

    const int tid  = threadIdx.x;
    const int lane = tid & 63;
    const int w    = tid >> 6;              // wave 0..7
    const int g    = lane >> 4;
    const int l15  = lane & 15;
    const int sx   = l15 & 7;

    // Balanced heavy+light strip pairing with head->XCD affinity (id%8 = bh%8)
    const int id    = blockIdx.x;
    const int bh    = id & 31;
    const int qi    = id >> 5;              // 0..15
    const int qt    = (id < 256) ? (15 - qi) : (qi - 8);
    const int qbase = qt * BQ;

    const char* kbase = ws + (size_t)bh * KBYTES_PER_HEAD;
    const char* vbase = ws + WS_V_OFF + (size_t)bh * KBYTES_PER_HEAD;

    // hoist Q fragments, pre-scaled into exp2 domain
    f16x8 aq[2];
    {
        const float* qrow = Q + ((size_t)bh * S_ + qbase + w * 16 + l15) * D_;
        #pragma unroll
        for (int kc = 0; kc < 2; ++kc) {
            const float4* p = (const float4*)(qrow + kc * 32 + g * 8);
            float4 x0 = p[0], x1 = p[1];
            f16x8 h;
            h[0] = (_Float16)(x0.x * QSCALE); h[1] = (_Float16)(x0.y * QSCALE);
            h[2] = (_Float16)(x0.z * QSCALE); h[3] = (_Float16)(x0.w * QSCALE);
            h[4] = (_Float16)(x1.x * QSCALE); h[5] = (_Float16)(x1.y * QSCALE);
            h[6] = (_Float16)(x1.z * QSCALE); h[7] = (_Float16)(x1.w * QSCALE);
            aq[kc] = h;
        }
    }

    f32x4 accO[4];
    #pragma unroll
    for (int i = 0; i < 4; ++i) accO[i] = (f32x4){0.f, 0.f, 0.f, 0.f};
    float m_r = -1e30f, l_r = 0.f;
    f32x4 accSA[4], accSB[4];

    const int nt  = 2 * qt + 2;             // 64-wide tiles; last two straddle the diagonal
    const int dqw = qbase + w * 16;         // wave q-row base

    // rotating buffer pointers: bQK = tile t, bPV = tile t-1, bST = stage target (t+1)
    _Float16* bQK = &SM[0][0];
    _Float16* bST = &SM[1][0];
    _Float16* bPV = &SM[2][0];

    // stage tile t into dst: 16 x 1KB chunks, 2 per wave (pre-swizzled source, linear dest)
    auto STAGE = [&](int t, _Float16* dst) {
        #pragma unroll
        for (int i = 0; i < 2; ++i) {
            const int c = w * 2 + i;
            const char* src = (c < 8 ? kbase + (size_t)t * 8192 + c * 1024
                                     : vbase + (size_t)t * 8192 + (c - 8) * 1024) + lane * 16;
            __builtin_amdgcn_global_load_lds((gu32*)src, (lu32*)(dst + c * 512), 16, 0, 0);
        }
    };
    auto SYNC = []() {
        asm volatile("s_waitcnt vmcnt(0)" ::: "memory");
        __builtin_amdgcn_s_barrier();
    };
    auto ROT = [&]() { _Float16* tmp = bPV; bPV = bQK; bQK = bST; bST = tmp; };

    STAGE(0, bQK);

    // ---- window 0: QK(0) -> A
    SYNC();
    STAGE(1, bST);
    if (qt == 0) qk_tile<true >(bQK, aq, accSA, g, l15, sx, dqw);
    else         qk_tile<false>(bQK, aq, accSA, g, l15, sx, 0);
    ROT();

    // ---- window 1: QK(1) -> B, SM+PV(0) from A
    SYNC();
    if (nt > 2) STAGE(2, bST);
    if (qt == 0) {
        qk_tile<true >(bQK, aq, accSB, g, l15, sx, dqw - 64);
        smpv_tile<true >(bPV, Pl[w], accSA, accO, m_r, l_r, g, l15, sx, dqw);
    } else {
        qk_tile<false>(bQK, aq, accSB, g, l15, sx, 0);
        smpv_tile<false>(bPV, Pl[w], accSA, accO, m_r, l_r, g, l15, sx, 0);
    }
    ROT();

    // ---- steady windows: tiles 2i (->A) and 2i+1 (->B), all unmasked
    for (int i = 1; i < qt; ++i) {
        const int t0 = 2 * i;
        SYNC();
        STAGE(t0 + 1, bST);
        qk_tile<false>(bQK, aq, accSA, g, l15, sx, 0);
        smpv_tile<false>(bPV, Pl[w], accSB, accO, m_r, l_r, g, l15, sx, 0);
        ROT();
        SYNC();
        STAGE(t0 + 2, bST);
        qk_tile<false>(bQK, aq, accSB, g, l15, sx, 0);
        smpv_tile<false>(bPV, Pl[w], accSA, accO, m_r, l_r, g, l15, sx, 0);
        ROT();
    }

    // ---- masked pair (tiles nt-2 -> A, nt-1 -> B), only for qt >= 1
    if (qt >= 1) {
        SYNC();
        STAGE(nt - 1, bST);
        qk_tile<true >(bQK, aq, accSA, g, l15, sx, dqw - (nt - 2) * 64);
        smpv_tile<false>(bPV, Pl[w], accSB, accO, m_r, l_r, g, l15, sx, 0);
        ROT();
        SYNC();
        qk_tile<true >(bQK, aq, accSB, g, l15, sx, dqw - (nt - 1) * 64);
        smpv_tile<true >(bPV, Pl[w], accSA, accO, m_r, l_r, g, l15, sx, dqw - (nt - 2) * 64);
        ROT();
    }

    // ---- epilogue window: SM+PV(nt-1) from B (V tile resident, Pl wave-local)
    smpv_tile<true>(bPV, Pl[w], accSB, accO, m_r, l_r, g, l15, sx, dqw - (nt - 1) * 64);

    // epilogue: finish deferred row-sum (once per kernel), store O
    float l = l_r;
    l += __shfl_xor(l, 16);
    l += __shfl_xor(l, 32);
    const float inv = 1.0f / l;
    float* orow = O + ((size_t)bh * S_ + qbase + w * 16 + l15) * D_;
    #pragma unroll
    for (int d = 0; d < 4; ++d) {
        f32x4 o = accO[d] * inv;
        *(f32x4*)&orow[d * 16 + g * 4] = o;
    }
}

extern "C" void kernel_launch(void* const* d_in, const int* in_sizes, int n_in,
                              void* d_out, int out_size, void* d_ws, size_t ws_size,
                              hipStream_t stream) {
    const float* q = (const float*)d_in[0];
    const float* k = (const float*)d_in[1];
    const float* v = (const float*)d_in[2];
    // d_in[3] (mask) intentionally never read — causality computed in-kernel
    float* o = (float*)d_out;
    char* ws = (char*)d_ws;

    if (ws_size < WS_NEED) return;

    const int kblocks = (B_ * H_ * S_ * 8) / 256;        // 1024
    const int vblocks = B_ * H_ * (S_ / 64);             // 1024
    prep_kv<<<kblocks + vblocks, 256, 0, stream>>>(k, v, ws);
    attn_main<<<(S_ / BQ) * B_ * H_, 512, 0, stream>>>(q, ws, o);
}